// Round 12
// baseline (306.072 us; speedup 1.0000x reference)
//
#include <hip/hip_runtime.h>
#include <hip/hip_bf16.h>
#include <hip/hip_fp16.h>

#define T_STEPS 12
#define N_NODES 10000
#define FDIM 128
#define M_ROWS (T_STEPS * N_NODES)

typedef __attribute__((ext_vector_type(8))) short short8v;
typedef __attribute__((ext_vector_type(8))) _Float16 half8v;
typedef __attribute__((ext_vector_type(2))) _Float16 half2v;
typedef __attribute__((ext_vector_type(4))) float f32x4;

// ---------------- CSR build (counting sort by dst), packed edges ----------------

__global__ __launch_bounds__(256) void k_count(const int* __restrict__ ei, int* __restrict__ cnt, int E) {
    int e = blockIdx.x * 256 + threadIdx.x;
    if (e < E) atomicAdd(&cnt[ei[E + e]], 1);
}

// 1 block, 256 threads; each thread scans a 40-element chunk serially.
__global__ __launch_bounds__(256) void k_scan2(const int* __restrict__ cnt, int* __restrict__ rowptr,
                                               int* __restrict__ cursor) {
    __shared__ int part[256];
    int tid = threadIdx.x;
    const int PER = 40;  // 256*40 = 10240 >= N_NODES
    int base = tid * PER;
    int s = 0;
#pragma unroll 8
    for (int q = 0; q < PER; ++q) {
        int idx = base + q;
        s += (idx < N_NODES) ? cnt[idx] : 0;
    }
    part[tid] = s;
    __syncthreads();
    for (int off = 1; off < 256; off <<= 1) {
        int v = (tid >= off) ? part[tid - off] : 0;
        __syncthreads();
        part[tid] += v;
        __syncthreads();
    }
    int run = (tid > 0) ? part[tid - 1] : 0;
#pragma unroll 8
    for (int q = 0; q < PER; ++q) {
        int idx = base + q;
        if (idx < N_NODES) {
            rowptr[idx] = run;
            cursor[idx] = run;
            run += cnt[idx];
        }
    }
    if (tid == 255) rowptr[N_NODES] = run;
}

__global__ __launch_bounds__(256) void k_fill(const int* __restrict__ ei, const float* __restrict__ ew,
                                              int* __restrict__ cursor, uint2* __restrict__ epack, int E) {
    int e = blockIdx.x * 256 + threadIdx.x;
    if (e < E) {
        int s = ei[e];
        int d = ei[E + e];
        int slot = atomicAdd(&cursor[d], 1);
        epack[slot] = make_uint2((unsigned)s, __builtin_bit_cast(unsigned, ew[e]));
    }
}

__global__ __launch_bounds__(256) void k_dinv(const int* __restrict__ rowptr, const uint2* __restrict__ epack,
                                              float* __restrict__ dinv) {
    int n = blockIdx.x * 256 + threadIdx.x;
    if (n < N_NODES) {
        int r0 = rowptr[n], r1 = rowptr[n + 1];
        float s = 0.f;
        for (int i = r0; i < r1; ++i) s += __builtin_bit_cast(float, epack[i].y);
        dinv[n] = (s > 0.f) ? rsqrtf(s) : 0.f;
    }
}

// finalize: epack[i] = {col*256 (byte offset of fp16 row), bits(dinv[n]*ew*dinv[col])}
__global__ __launch_bounds__(256) void k_scale(const int* __restrict__ rowptr, uint2* __restrict__ epack,
                                               const float* __restrict__ dinv) {
    int n = blockIdx.x * 256 + threadIdx.x;
    if (n < N_NODES) {
        int r0 = rowptr[n], r1 = rowptr[n + 1];
        float dn = dinv[n];
        for (int i = r0; i < r1; ++i) {
            uint2 e = epack[i];
            float v = dn * __builtin_bit_cast(float, e.y) * dinv[e.x];
            epack[i] = make_uint2(e.x * 256u, __builtin_bit_cast(unsigned, v));
        }
    }
}

// ---------------- W pre-split: f32 -> fp16 hi + fp16 lo in MFMA B-frag layout ----------------

__global__ __launch_bounds__(256) void k_wsplit4(const float* __restrict__ Wa, const float* __restrict__ Wb,
                                                 const float* __restrict__ Wc, const float* __restrict__ Wd,
                                                 short* __restrict__ base) {
    int wsel = blockIdx.y;
    const float* W = (wsel == 0) ? Wa : (wsel == 1) ? Wb : (wsel == 2) ? Wc : Wd;
    short* Whf = base + (size_t)wsel * 2 * FDIM * FDIM;
    short* Wlf = Whf + FDIM * FDIM;
    int idx = blockIdx.x * 256 + threadIdx.x;  // 16384
    int k = idx >> 7, col = idx & 127;
    int s = k >> 5, kb = (k >> 3) & 3, j = k & 7;
    float w = W[(size_t)k * FDIM + col];
    _Float16 hi = (_Float16)w;
    _Float16 lo = (_Float16)(w - (float)hi);
    size_t oi = (size_t)(((s * 4 + kb) * 128 + col)) * 8 + j;
    Whf[oi] = __builtin_bit_cast(short, hi);
    Wlf[oi] = __builtin_bit_cast(short, lo);
}

// ---------------- fp16 MFMA GEMM: C[M,128] = A[M,128] @ (Whi+Wlo) ----------------
// 16-row waves (1 m-tile): 7500 waves total -> ~7.3 waves/SIMD (2x the old
// 32-row-wave config) to hide A-load latency. acc = 8 f32x4 (32 VGPR).

template <typename IN_T, typename OUT_T>
__global__ __launch_bounds__(256) void k_gemm_f16(const IN_T* __restrict__ A,
                                                  const short* __restrict__ Whf,
                                                  const short* __restrict__ Wlf,
                                                  OUT_T* __restrict__ C, int Mrows) {
    int tid = threadIdx.x;
    int wave = tid >> 6, lane = tid & 63;
    int lr = lane & 15, kb = lane >> 4;
    int row0 = blockIdx.x * 64 + wave * 16;  // wave owns 16 rows

    f32x4 acc[8];
#pragma unroll
    for (int n = 0; n < 8; ++n) acc[n] = (f32x4){0.f, 0.f, 0.f, 0.f};

    int r = row0 + lr;
    if (r > Mrows - 1) r = Mrows - 1;

#pragma unroll
    for (int s = 0; s < 4; ++s) {
        half8v a;
        const IN_T* ap = &A[(size_t)r * FDIM + s * 32 + kb * 8];
        if constexpr (sizeof(IN_T) == 4) {
            float4 x0 = *(const float4*)ap;
            float4 x1 = *(const float4*)(ap + 4);
            a[0] = (_Float16)x0.x; a[1] = (_Float16)x0.y;
            a[2] = (_Float16)x0.z; a[3] = (_Float16)x0.w;
            a[4] = (_Float16)x1.x; a[5] = (_Float16)x1.y;
            a[6] = (_Float16)x1.z; a[7] = (_Float16)x1.w;
        } else {
            a = __builtin_bit_cast(half8v, *(const short8v*)ap);
        }
#pragma unroll
        for (int n = 0; n < 8; ++n) {
            size_t wo = (size_t)(((s * 4 + kb) * 128 + n * 16 + lr)) * 8;
            half8v wh = __builtin_bit_cast(half8v, *(const short8v*)&Whf[wo]);
            half8v wl = __builtin_bit_cast(half8v, *(const short8v*)&Wlf[wo]);
            acc[n] = __builtin_amdgcn_mfma_f32_16x16x32_f16(a, wh, acc[n], 0, 0, 0);
            acc[n] = __builtin_amdgcn_mfma_f32_16x16x32_f16(a, wl, acc[n], 0, 0, 0);
        }
    }
    // D layout: col = lane&15 (+16n), row = row0 + (lane>>4)*4 + q
#pragma unroll
    for (int q = 0; q < 4; ++q) {
        int ro = row0 + kb * 4 + q;
        if (ro < Mrows) {
#pragma unroll
            for (int n = 0; n < 8; ++n)
                C[(size_t)ro * FDIM + n * 16 + lr] = (OUT_T)acc[n][q];
        }
    }
}

// ---------------- spatial aggregation: XCD-pinned, scalar edge stream, 16-deep gathers ----------------

#define NPB 20
#define NB_HALF 250

__global__ __launch_bounds__(128) void k_aggx(const char* __restrict__ Sbytes,
                                              const int* __restrict__ rowptr,
                                              const uint2* __restrict__ epack,
                                              const float* __restrict__ bias, __half* __restrict__ out,
                                              int do_relu) {
    int bid = blockIdx.x;
    int x = bid & 7;
    int j = bid >> 3;          // 0..749
    int unit = j / NB_HALF;    // 0,1,2
    int nb = j - unit * NB_HALF;
    int t, n0;
    if (unit == 2) { t = 8 + (x >> 1); n0 = (x & 1) * 5000 + nb * NPB; }
    else           { t = x;            n0 = unit * 5000 + nb * NPB; }

    int wave = threadIdx.x >> 6, lane = threadIdx.x & 63;
    const char* St = Sbytes + (size_t)t * N_NODES * 256;  // 256 B per fp16 row
    unsigned lane4 = (unsigned)lane * 4u;
    float b0 = bias[2 * lane], b1 = bias[2 * lane + 1];

    int nbase = n0 + wave * (NPB / 2);
    for (int nn = 0; nn < NPB / 2; ++nn) {
        int n = nbase + nn;
        int r0 = __builtin_amdgcn_readfirstlane(rowptr[n]);
        int r1 = __builtin_amdgcn_readfirstlane(rowptr[n + 1]);
        float a0 = 0.f, a1 = 0.f;
        int i = r0;
        while (i + 16 <= r1) {
            unsigned sx[16]; float sv[16];
#pragma unroll
            for (int q = 0; q < 16; ++q) {
                uint2 e = epack[i + q];
                sx[q] = e.x;
                sv[q] = __builtin_bit_cast(float, e.y);
            }
            unsigned u[16];
#pragma unroll
            for (int q = 0; q < 16; ++q)
                u[q] = *(const unsigned*)(St + (sx[q] + lane4));
#pragma unroll
            for (int q = 0; q < 16; ++q) {
                half2v h = __builtin_bit_cast(half2v, u[q]);
                a0 = fmaf(sv[q], (float)h[0], a0);
                a1 = fmaf(sv[q], (float)h[1], a1);
            }
            i += 16;
        }
        while (i < r1) {
            unsigned sx[8]; float sv[8];
#pragma unroll
            for (int q = 0; q < 8; ++q) {
                int ii = i + q;
                int ic = (ii < r1) ? ii : r1 - 1;
                uint2 e = epack[ic];
                sx[q] = e.x;
                sv[q] = (ii < r1) ? __builtin_bit_cast(float, e.y) : 0.f;
            }
            unsigned u[8];
#pragma unroll
            for (int q = 0; q < 8; ++q)
                u[q] = *(const unsigned*)(St + (sx[q] + lane4));
#pragma unroll
            for (int q = 0; q < 8; ++q) {
                half2v h = __builtin_bit_cast(half2v, u[q]);
                a0 = fmaf(sv[q], (float)h[0], a0);
                a1 = fmaf(sv[q], (float)h[1], a1);
            }
            i += 8;
        }
        float o0 = a0 + b0, o1 = a1 + b1;
        if (do_relu) { o0 = fmaxf(o0, 0.f); o1 = fmaxf(o1, 0.f); }
        __half2 h = __floats2half2_rn(o0, o1);
        unsigned uo = __builtin_bit_cast(unsigned, h);
        __builtin_nontemporal_store(uo, (unsigned*)&out[((size_t)t * N_NODES + n) * FDIM + 2 * lane]);
    }
}

// ---------------- temporal aggregation (chain graph, closed-form norm), fp16 I/O ----------------

__device__ __forceinline__ void tagg_core(float2 (&s)[T_STEPS], float b0, float b1,
                                          float2 (&o)[T_STEPS]) {
    const float IS2 = 0.70710678118654752f;
#pragma unroll
    for (int t = 0; t < T_STEPS; ++t) {
        float dt = (t == 0 || t == T_STEPS - 1) ? 1.f : IS2;
        float a0 = 0.f, a1 = 0.f;
        if (t > 0) {
            float dp = (t - 1 == 0) ? 1.f : IS2;
            a0 += dp * s[t - 1].x; a1 += dp * s[t - 1].y;
        }
        if (t < T_STEPS - 1) {
            float dn = (t + 1 == T_STEPS - 1) ? 1.f : IS2;
            a0 += dn * s[t + 1].x; a1 += dn * s[t + 1].y;
        }
        o[t].x = dt * a0 + b0;
        o[t].y = dt * a1 + b1;
    }
}

__global__ __launch_bounds__(256) void k_tagg_relu(const __half2* __restrict__ S2,
                                                   const float* __restrict__ bias,
                                                   __half2* __restrict__ out) {
    int p = blockIdx.x * 256 + threadIdx.x;
    if (p >= N_NODES * 64) return;
    int c2 = p & 63;
    float b0 = bias[2 * c2], b1 = bias[2 * c2 + 1];
    float2 s[T_STEPS], o[T_STEPS];
#pragma unroll
    for (int t = 0; t < T_STEPS; ++t) s[t] = __half22float2(S2[(size_t)t * N_NODES * 64 + p]);
    tagg_core(s, b0, b1, o);
#pragma unroll
    for (int t = 0; t < T_STEPS; ++t) {
        float o0 = fmaxf(o[t].x, 0.f), o1 = fmaxf(o[t].y, 0.f);
        out[(size_t)t * N_NODES * 64 + p] = __floats2half2_rn(o0, o1);
    }
}

__global__ __launch_bounds__(256) void k_tagg_tanh(const __half2* __restrict__ S2,
                                                   const float* __restrict__ bias,
                                                   float* __restrict__ out) {
    int p = blockIdx.x * 256 + threadIdx.x;
    if (p >= N_NODES * 64) return;
    int c2 = p & 63;
    float b0 = bias[2 * c2], b1 = bias[2 * c2 + 1];
    float2 s[T_STEPS], o[T_STEPS];
#pragma unroll
    for (int t = 0; t < T_STEPS; ++t) s[t] = __half22float2(S2[(size_t)t * N_NODES * 64 + p]);
    tagg_core(s, b0, b1, o);
#pragma unroll
    for (int t = 0; t < T_STEPS; ++t) {
        float2 r = make_float2(tanhf(o[t].x), tanhf(o[t].y));
        *(float2*)&out[(size_t)t * N_NODES * FDIM + 2 * (size_t)p] = r;
    }
}

// ---------------- launch ----------------

extern "C" void kernel_launch(void* const* d_in, const int* in_sizes, int n_in,
                              void* d_out, int out_size, void* d_ws, size_t ws_size,
                              hipStream_t stream) {
    const float* x   = (const float*)d_in[0];
    const int*   ei  = (const int*)d_in[1];
    const float* ew  = (const float*)d_in[2];
    const float* W1  = (const float*)d_in[3];
    const float* b1  = (const float*)d_in[4];
    const float* W2  = (const float*)d_in[5];
    const float* b2  = (const float*)d_in[6];
    const float* Wt1 = (const float*)d_in[7];
    const float* bt1 = (const float*)d_in[8];
    const float* Wt2 = (const float*)d_in[9];
    const float* bt2 = (const float*)d_in[10];
    float*  outF = (float*)d_out;
    __half* Sh   = (__half*)d_out;  // fp16 GEMM outputs alias front half of d_out
    const int E = in_sizes[2];

    char* w = (char*)d_ws;
    __half* bufH = (__half*)w;                 // fp16 agg/tagg outputs (GEMM A inputs)
    size_t off   = (size_t)M_ROWS * FDIM * 2;
    __half* S2h  = (__half*)(w + off); off += (size_t)M_ROWS * FDIM * 2;  // GEMM4 out
    int* cnt     = (int*)(w + off); off += (size_t)N_NODES * 4;
    int* rowptr  = (int*)(w + off); off += (size_t)(N_NODES + 1) * 4;
    int* cursor  = (int*)(w + off); off += (size_t)N_NODES * 4;
    uint2* epack = (uint2*)(w + off); off += (size_t)E * 8;
    float* dinv  = (float*)(w + off); off += (size_t)N_NODES * 4;
    short* Wsp   = (short*)(w + off); off += (size_t)8 * FDIM * FDIM * 2;  // 4 x (hi,lo)
    const size_t WSZ = (size_t)FDIM * FDIM;
    short* W1h = Wsp;            short* W1l = Wsp + WSZ;
    short* W2h = Wsp + 2 * WSZ;  short* W2l = Wsp + 3 * WSZ;
    short* Wt1h = Wsp + 4 * WSZ; short* Wt1l = Wsp + 5 * WSZ;
    short* Wt2h = Wsp + 6 * WSZ; short* Wt2l = Wsp + 7 * WSZ;

    hipMemsetAsync(cnt, 0, (size_t)N_NODES * 4, stream);
    int eb = (E + 255) / 256;
    int nb = (N_NODES + 255) / 256;
    k_count<<<eb, 256, 0, stream>>>(ei, cnt, E);
    k_scan2<<<1, 256, 0, stream>>>(cnt, rowptr, cursor);
    k_fill<<<eb, 256, 0, stream>>>(ei, ew, cursor, epack, E);
    k_dinv<<<nb, 256, 0, stream>>>(rowptr, epack, dinv);
    k_scale<<<nb, 256, 0, stream>>>(rowptr, epack, dinv);

    dim3 wgrid((FDIM * FDIM) / 256, 4);
    k_wsplit4<<<wgrid, 256, 0, stream>>>(W1, W2, Wt1, Wt2, Wsp);

    int gb = (M_ROWS + 63) / 64;      // 1875 blocks, 64 rows each (4 waves x 16 rows)
    int tb = (N_NODES * 64 + 255) / 256;
    int ab = 8 * 3 * NB_HALF;         // 6000 blocks, XCD-pinned decode inside

    // spatial layer 1: Sh = fp16(X@W1) ; bufH = fp16(relu(A*Sh + b1))
    k_gemm_f16<float, __half><<<gb, 256, 0, stream>>>(x, W1h, W1l, Sh, M_ROWS);
    k_aggx<<<ab, 128, 0, stream>>>((const char*)Sh, rowptr, epack, b1, bufH, 1);
    // spatial layer 2
    k_gemm_f16<__half, __half><<<gb, 256, 0, stream>>>(bufH, W2h, W2l, Sh, M_ROWS);
    k_aggx<<<ab, 128, 0, stream>>>((const char*)Sh, rowptr, epack, b2, bufH, 0);
    // temporal layer 1: Sh = fp16(bufH@Wt1) ; bufH = fp16(relu(Tagg(Sh)+bt1))
    k_gemm_f16<__half, __half><<<gb, 256, 0, stream>>>(bufH, Wt1h, Wt1l, Sh, M_ROWS);
    k_tagg_relu<<<tb, 256, 0, stream>>>((const __half2*)Sh, bt1, (__half2*)bufH);
    // temporal layer 2: S2h = fp16(bufH@Wt2) ; out = tanh(Tagg(S2h)+bt2)  (f32 to d_out)
    k_gemm_f16<__half, __half><<<gb, 256, 0, stream>>>(bufH, Wt2h, Wt2l, S2h, M_ROWS);
    k_tagg_tanh<<<tb, 256, 0, stream>>>((const __half2*)S2h, bt2, outF);
}

// Round 13
// 270.846 us; speedup vs baseline: 1.1301x; 1.1301x over previous
//
#include <hip/hip_runtime.h>
#include <hip/hip_bf16.h>
#include <hip/hip_fp16.h>

#define T_STEPS 12
#define N_NODES 10000
#define FDIM 128
#define M_ROWS (T_STEPS * N_NODES)

typedef __attribute__((ext_vector_type(8))) short short8v;
typedef __attribute__((ext_vector_type(8))) _Float16 half8v;
typedef __attribute__((ext_vector_type(2))) _Float16 half2v;
typedef __attribute__((ext_vector_type(4))) float f32x4;

// async global->LDS, 16 B per lane; LDS dest is wave-uniform base + lane*16
__device__ __forceinline__ void gload_lds16(const void* g, void* l) {
    __builtin_amdgcn_global_load_lds(
        (const __attribute__((address_space(1))) unsigned int*)g,
        (__attribute__((address_space(3))) unsigned int*)l,
        16, 0, 0);
}

// ---------------- CSR build (counting sort by dst), packed edges ----------------

__global__ __launch_bounds__(256) void k_count(const int* __restrict__ ei, int* __restrict__ cnt, int E) {
    int e = blockIdx.x * 256 + threadIdx.x;
    if (e < E) atomicAdd(&cnt[ei[E + e]], 1);
}

// 1 block, 256 threads; each thread scans a 40-element chunk serially.
__global__ __launch_bounds__(256) void k_scan2(const int* __restrict__ cnt, int* __restrict__ rowptr,
                                               int* __restrict__ cursor) {
    __shared__ int part[256];
    int tid = threadIdx.x;
    const int PER = 40;  // 256*40 = 10240 >= N_NODES
    int base = tid * PER;
    int s = 0;
#pragma unroll 8
    for (int q = 0; q < PER; ++q) {
        int idx = base + q;
        s += (idx < N_NODES) ? cnt[idx] : 0;
    }
    part[tid] = s;
    __syncthreads();
    for (int off = 1; off < 256; off <<= 1) {
        int v = (tid >= off) ? part[tid - off] : 0;
        __syncthreads();
        part[tid] += v;
        __syncthreads();
    }
    int run = (tid > 0) ? part[tid - 1] : 0;
#pragma unroll 8
    for (int q = 0; q < PER; ++q) {
        int idx = base + q;
        if (idx < N_NODES) {
            rowptr[idx] = run;
            cursor[idx] = run;
            run += cnt[idx];
        }
    }
    if (tid == 255) rowptr[N_NODES] = run;
}

__global__ __launch_bounds__(256) void k_fill(const int* __restrict__ ei, const float* __restrict__ ew,
                                              int* __restrict__ cursor, uint2* __restrict__ epack, int E) {
    int e = blockIdx.x * 256 + threadIdx.x;
    if (e < E) {
        int s = ei[e];
        int d = ei[E + e];
        int slot = atomicAdd(&cursor[d], 1);
        epack[slot] = make_uint2((unsigned)s, __builtin_bit_cast(unsigned, ew[e]));
    }
}

__global__ __launch_bounds__(256) void k_dinv(const int* __restrict__ rowptr, const uint2* __restrict__ epack,
                                              float* __restrict__ dinv) {
    int n = blockIdx.x * 256 + threadIdx.x;
    if (n < N_NODES) {
        int r0 = rowptr[n], r1 = rowptr[n + 1];
        float s = 0.f;
        for (int i = r0; i < r1; ++i) s += __builtin_bit_cast(float, epack[i].y);
        dinv[n] = (s > 0.f) ? rsqrtf(s) : 0.f;
    }
}

// finalize: epack[i] = {col*256 (byte offset of fp16 row), bits(dinv[n]*ew*dinv[col])}
__global__ __launch_bounds__(256) void k_scale(const int* __restrict__ rowptr, uint2* __restrict__ epack,
                                               const float* __restrict__ dinv) {
    int n = blockIdx.x * 256 + threadIdx.x;
    if (n < N_NODES) {
        int r0 = rowptr[n], r1 = rowptr[n + 1];
        float dn = dinv[n];
        for (int i = r0; i < r1; ++i) {
            uint2 e = epack[i];
            float v = dn * __builtin_bit_cast(float, e.y) * dinv[e.x];
            epack[i] = make_uint2(e.x * 256u, __builtin_bit_cast(unsigned, v));
        }
    }
}

// ---------------- W pre-split: f32 -> fp16 hi + fp16 lo in MFMA B-frag layout ----------------

__global__ __launch_bounds__(256) void k_wsplit4(const float* __restrict__ Wa, const float* __restrict__ Wb,
                                                 const float* __restrict__ Wc, const float* __restrict__ Wd,
                                                 short* __restrict__ base) {
    int wsel = blockIdx.y;
    const float* W = (wsel == 0) ? Wa : (wsel == 1) ? Wb : (wsel == 2) ? Wc : Wd;
    short* Whf = base + (size_t)wsel * 2 * FDIM * FDIM;
    short* Wlf = Whf + FDIM * FDIM;
    int idx = blockIdx.x * 256 + threadIdx.x;  // 16384
    int k = idx >> 7, col = idx & 127;
    int s = k >> 5, kb = (k >> 3) & 3, j = k & 7;
    float w = W[(size_t)k * FDIM + col];
    _Float16 hi = (_Float16)w;
    _Float16 lo = (_Float16)(w - (float)hi);
    size_t oi = (size_t)(((s * 4 + kb) * 128 + col)) * 8 + j;
    Whf[oi] = __builtin_bit_cast(short, hi);
    Wlf[oi] = __builtin_bit_cast(short, lo);
}

// ---------------- fp16 MFMA GEMM: C[M,128] = A[M,128] @ (Whi+Wlo), LDS-staged W ----------------
// 256 threads = 4 waves; wave owns 32 rows x 128 cols (2 m x 8 n tiles of 16x16).
// W fragments (hi||lo, 64 KB, already fragment-linear) staged into LDS once per
// block via global_load_lds width=16; fragment reads become ds_read_b128.
// 64 KB LDS -> 2 blocks/CU (8 waves/CU).

template <typename IN_T, typename OUT_T>
__global__ __launch_bounds__(256) void k_gemm_f16(const IN_T* __restrict__ A,
                                                  const short* __restrict__ Whf,
                                                  const short* __restrict__ Wlf,
                                                  OUT_T* __restrict__ C, int Mrows) {
    __shared__ short WsL[2 * FDIM * FDIM];  // hi at 0, lo at 16384 (halfwords)
    int tid = threadIdx.x;
    int wave = tid >> 6, lane = tid & 63;
    int lr = lane & 15, kb = lane >> 4;
    int rbase = blockIdx.x * 128 + wave * 32;

    // stage Whf (32 KB) and Wlf (32 KB) linearly into LDS
    {
        const char* srcH = (const char*)Whf;
        const char* srcL = (const char*)Wlf;
        char* dst = (char*)WsL;
#pragma unroll
        for (int it = 0; it < 8; ++it) {
            int chunk = (it * 4 + wave) * 1024;  // 64 lanes x 16 B per wave-issue
            gload_lds16(srcH + chunk + lane * 16, dst + chunk);
            gload_lds16(srcL + chunk + lane * 16, dst + 32768 + chunk);
        }
    }

    f32x4 acc[2][8];
#pragma unroll
    for (int m = 0; m < 2; ++m)
#pragma unroll
        for (int n = 0; n < 8; ++n) acc[m][n] = (f32x4){0.f, 0.f, 0.f, 0.f};

    __syncthreads();  // drains global_load_lds (vmcnt) + barrier

#pragma unroll
    for (int s = 0; s < 4; ++s) {
        half8v a[2];
#pragma unroll
        for (int m = 0; m < 2; ++m) {
            int r = rbase + m * 16 + lr;
            if (r > Mrows - 1) r = Mrows - 1;
            const IN_T* ap = &A[(size_t)r * FDIM + s * 32 + kb * 8];
            if constexpr (sizeof(IN_T) == 4) {
                float4 x0 = *(const float4*)ap;
                float4 x1 = *(const float4*)(ap + 4);
                a[m][0] = (_Float16)x0.x; a[m][1] = (_Float16)x0.y;
                a[m][2] = (_Float16)x0.z; a[m][3] = (_Float16)x0.w;
                a[m][4] = (_Float16)x1.x; a[m][5] = (_Float16)x1.y;
                a[m][6] = (_Float16)x1.z; a[m][7] = (_Float16)x1.w;
            } else {
                a[m] = __builtin_bit_cast(half8v, *(const short8v*)ap);
            }
        }
#pragma unroll
        for (int n = 0; n < 8; ++n) {
            int wo = (((s * 4 + kb) * 128 + n * 16 + lr)) * 8;
            half8v wh = __builtin_bit_cast(half8v, *(const short8v*)&WsL[wo]);
            half8v wl = __builtin_bit_cast(half8v, *(const short8v*)&WsL[16384 + wo]);
#pragma unroll
            for (int m = 0; m < 2; ++m) {
                acc[m][n] = __builtin_amdgcn_mfma_f32_16x16x32_f16(a[m], wh, acc[m][n], 0, 0, 0);
                acc[m][n] = __builtin_amdgcn_mfma_f32_16x16x32_f16(a[m], wl, acc[m][n], 0, 0, 0);
            }
        }
    }
    // D layout: col = lane&15 (+16n), row = rbase + 16m + (lane>>4)*4 + q
#pragma unroll
    for (int m = 0; m < 2; ++m)
#pragma unroll
        for (int q = 0; q < 4; ++q) {
            int r = rbase + m * 16 + kb * 4 + q;
            if (r < Mrows) {
#pragma unroll
                for (int n = 0; n < 8; ++n)
                    C[(size_t)r * FDIM + n * 16 + lr] = (OUT_T)acc[m][n][q];
            }
        }
}

// ---------------- spatial aggregation: XCD-pinned, scalar edge stream, 16-deep gathers ----------------

#define NPB 20
#define NB_HALF 250

__global__ __launch_bounds__(128) void k_aggx(const char* __restrict__ Sbytes,
                                              const int* __restrict__ rowptr,
                                              const uint2* __restrict__ epack,
                                              const float* __restrict__ bias, __half* __restrict__ out,
                                              int do_relu) {
    int bid = blockIdx.x;
    int x = bid & 7;
    int j = bid >> 3;          // 0..749
    int unit = j / NB_HALF;    // 0,1,2
    int nb = j - unit * NB_HALF;
    int t, n0;
    if (unit == 2) { t = 8 + (x >> 1); n0 = (x & 1) * 5000 + nb * NPB; }
    else           { t = x;            n0 = unit * 5000 + nb * NPB; }

    int wave = threadIdx.x >> 6, lane = threadIdx.x & 63;
    const char* St = Sbytes + (size_t)t * N_NODES * 256;  // 256 B per fp16 row
    unsigned lane4 = (unsigned)lane * 4u;
    float b0 = bias[2 * lane], b1 = bias[2 * lane + 1];

    int nbase = n0 + wave * (NPB / 2);
    for (int nn = 0; nn < NPB / 2; ++nn) {
        int n = nbase + nn;
        int r0 = __builtin_amdgcn_readfirstlane(rowptr[n]);
        int r1 = __builtin_amdgcn_readfirstlane(rowptr[n + 1]);
        float a0 = 0.f, a1 = 0.f;
        int i = r0;
        while (i + 16 <= r1) {
            unsigned sx[16]; float sv[16];
#pragma unroll
            for (int q = 0; q < 16; ++q) {
                uint2 e = epack[i + q];
                sx[q] = e.x;
                sv[q] = __builtin_bit_cast(float, e.y);
            }
            unsigned u[16];
#pragma unroll
            for (int q = 0; q < 16; ++q)
                u[q] = *(const unsigned*)(St + (sx[q] + lane4));
#pragma unroll
            for (int q = 0; q < 16; ++q) {
                half2v h = __builtin_bit_cast(half2v, u[q]);
                a0 = fmaf(sv[q], (float)h[0], a0);
                a1 = fmaf(sv[q], (float)h[1], a1);
            }
            i += 16;
        }
        while (i < r1) {
            unsigned sx[8]; float sv[8];
#pragma unroll
            for (int q = 0; q < 8; ++q) {
                int ii = i + q;
                int ic = (ii < r1) ? ii : r1 - 1;
                uint2 e = epack[ic];
                sx[q] = e.x;
                sv[q] = (ii < r1) ? __builtin_bit_cast(float, e.y) : 0.f;
            }
            unsigned u[8];
#pragma unroll
            for (int q = 0; q < 8; ++q)
                u[q] = *(const unsigned*)(St + (sx[q] + lane4));
#pragma unroll
            for (int q = 0; q < 8; ++q) {
                half2v h = __builtin_bit_cast(half2v, u[q]);
                a0 = fmaf(sv[q], (float)h[0], a0);
                a1 = fmaf(sv[q], (float)h[1], a1);
            }
            i += 8;
        }
        float o0 = a0 + b0, o1 = a1 + b1;
        if (do_relu) { o0 = fmaxf(o0, 0.f); o1 = fmaxf(o1, 0.f); }
        __half2 h = __floats2half2_rn(o0, o1);
        unsigned uo = __builtin_bit_cast(unsigned, h);
        __builtin_nontemporal_store(uo, (unsigned*)&out[((size_t)t * N_NODES + n) * FDIM + 2 * lane]);
    }
}

// ---------------- temporal aggregation (chain graph, closed-form norm), fp16 I/O ----------------

__device__ __forceinline__ void tagg_core(float2 (&s)[T_STEPS], float b0, float b1,
                                          float2 (&o)[T_STEPS]) {
    const float IS2 = 0.70710678118654752f;
#pragma unroll
    for (int t = 0; t < T_STEPS; ++t) {
        float dt = (t == 0 || t == T_STEPS - 1) ? 1.f : IS2;
        float a0 = 0.f, a1 = 0.f;
        if (t > 0) {
            float dp = (t - 1 == 0) ? 1.f : IS2;
            a0 += dp * s[t - 1].x; a1 += dp * s[t - 1].y;
        }
        if (t < T_STEPS - 1) {
            float dn = (t + 1 == T_STEPS - 1) ? 1.f : IS2;
            a0 += dn * s[t + 1].x; a1 += dn * s[t + 1].y;
        }
        o[t].x = dt * a0 + b0;
        o[t].y = dt * a1 + b1;
    }
}

__global__ __launch_bounds__(256) void k_tagg_relu(const __half2* __restrict__ S2,
                                                   const float* __restrict__ bias,
                                                   __half2* __restrict__ out) {
    int p = blockIdx.x * 256 + threadIdx.x;
    if (p >= N_NODES * 64) return;
    int c2 = p & 63;
    float b0 = bias[2 * c2], b1 = bias[2 * c2 + 1];
    float2 s[T_STEPS], o[T_STEPS];
#pragma unroll
    for (int t = 0; t < T_STEPS; ++t) s[t] = __half22float2(S2[(size_t)t * N_NODES * 64 + p]);
    tagg_core(s, b0, b1, o);
#pragma unroll
    for (int t = 0; t < T_STEPS; ++t) {
        float o0 = fmaxf(o[t].x, 0.f), o1 = fmaxf(o[t].y, 0.f);
        out[(size_t)t * N_NODES * 64 + p] = __floats2half2_rn(o0, o1);
    }
}

__global__ __launch_bounds__(256) void k_tagg_tanh(const __half2* __restrict__ S2,
                                                   const float* __restrict__ bias,
                                                   float* __restrict__ out) {
    int p = blockIdx.x * 256 + threadIdx.x;
    if (p >= N_NODES * 64) return;
    int c2 = p & 63;
    float b0 = bias[2 * c2], b1 = bias[2 * c2 + 1];
    float2 s[T_STEPS], o[T_STEPS];
#pragma unroll
    for (int t = 0; t < T_STEPS; ++t) s[t] = __half22float2(S2[(size_t)t * N_NODES * 64 + p]);
    tagg_core(s, b0, b1, o);
#pragma unroll
    for (int t = 0; t < T_STEPS; ++t) {
        float2 r = make_float2(tanhf(o[t].x), tanhf(o[t].y));
        *(float2*)&out[(size_t)t * N_NODES * FDIM + 2 * (size_t)p] = r;
    }
}

// ---------------- launch ----------------

extern "C" void kernel_launch(void* const* d_in, const int* in_sizes, int n_in,
                              void* d_out, int out_size, void* d_ws, size_t ws_size,
                              hipStream_t stream) {
    const float* x   = (const float*)d_in[0];
    const int*   ei  = (const int*)d_in[1];
    const float* ew  = (const float*)d_in[2];
    const float* W1  = (const float*)d_in[3];
    const float* b1  = (const float*)d_in[4];
    const float* W2  = (const float*)d_in[5];
    const float* b2  = (const float*)d_in[6];
    const float* Wt1 = (const float*)d_in[7];
    const float* bt1 = (const float*)d_in[8];
    const float* Wt2 = (const float*)d_in[9];
    const float* bt2 = (const float*)d_in[10];
    float*  outF = (float*)d_out;
    __half* Sh   = (__half*)d_out;  // fp16 GEMM outputs alias front half of d_out
    const int E = in_sizes[2];

    char* w = (char*)d_ws;
    __half* bufH = (__half*)w;                 // fp16 agg/tagg outputs (GEMM A inputs)
    size_t off   = (size_t)M_ROWS * FDIM * 2;
    __half* S2h  = (__half*)(w + off); off += (size_t)M_ROWS * FDIM * 2;  // GEMM4 out
    int* cnt     = (int*)(w + off); off += (size_t)N_NODES * 4;
    int* rowptr  = (int*)(w + off); off += (size_t)(N_NODES + 1) * 4;
    int* cursor  = (int*)(w + off); off += (size_t)N_NODES * 4;
    uint2* epack = (uint2*)(w + off); off += (size_t)E * 8;
    float* dinv  = (float*)(w + off); off += (size_t)N_NODES * 4;
    short* Wsp   = (short*)(w + off); off += (size_t)8 * FDIM * FDIM * 2;  // 4 x (hi,lo)
    const size_t WSZ = (size_t)FDIM * FDIM;
    short* W1h = Wsp;            short* W1l = Wsp + WSZ;
    short* W2h = Wsp + 2 * WSZ;  short* W2l = Wsp + 3 * WSZ;
    short* Wt1h = Wsp + 4 * WSZ; short* Wt1l = Wsp + 5 * WSZ;
    short* Wt2h = Wsp + 6 * WSZ; short* Wt2l = Wsp + 7 * WSZ;

    hipMemsetAsync(cnt, 0, (size_t)N_NODES * 4, stream);
    int eb = (E + 255) / 256;
    int nb = (N_NODES + 255) / 256;
    k_count<<<eb, 256, 0, stream>>>(ei, cnt, E);
    k_scan2<<<1, 256, 0, stream>>>(cnt, rowptr, cursor);
    k_fill<<<eb, 256, 0, stream>>>(ei, ew, cursor, epack, E);
    k_dinv<<<nb, 256, 0, stream>>>(rowptr, epack, dinv);
    k_scale<<<nb, 256, 0, stream>>>(rowptr, epack, dinv);

    dim3 wgrid((FDIM * FDIM) / 256, 4);
    k_wsplit4<<<wgrid, 256, 0, stream>>>(W1, W2, Wt1, Wt2, Wsp);

    int gb = (M_ROWS + 127) / 128;    // 938 blocks, 128 rows each (4 waves x 32 rows)
    int tb = (N_NODES * 64 + 255) / 256;
    int ab = 8 * 3 * NB_HALF;         // 6000 blocks, XCD-pinned decode inside

    // spatial layer 1: Sh = fp16(X@W1) ; bufH = fp16(relu(A*Sh + b1))
    k_gemm_f16<float, __half><<<gb, 256, 0, stream>>>(x, W1h, W1l, Sh, M_ROWS);
    k_aggx<<<ab, 128, 0, stream>>>((const char*)Sh, rowptr, epack, b1, bufH, 1);
    // spatial layer 2
    k_gemm_f16<__half, __half><<<gb, 256, 0, stream>>>(bufH, W2h, W2l, Sh, M_ROWS);
    k_aggx<<<ab, 128, 0, stream>>>((const char*)Sh, rowptr, epack, b2, bufH, 0);
    // temporal layer 1: Sh = fp16(bufH@Wt1) ; bufH = fp16(relu(Tagg(Sh)+bt1))
    k_gemm_f16<__half, __half><<<gb, 256, 0, stream>>>(bufH, Wt1h, Wt1l, Sh, M_ROWS);
    k_tagg_relu<<<tb, 256, 0, stream>>>((const __half2*)Sh, bt1, (__half2*)bufH);
    // temporal layer 2: S2h = fp16(bufH@Wt2) ; out = tanh(Tagg(S2h)+bt2)  (f32 to d_out)
    k_gemm_f16<__half, __half><<<gb, 256, 0, stream>>>(bufH, Wt2h, Wt2l, S2h, M_ROWS);
    k_tagg_tanh<<<tb, 256, 0, stream>>>((const __half2*)S2h, bt2, outF);
}

// Round 14
// 260.785 us; speedup vs baseline: 1.1737x; 1.0386x over previous
//
#include <hip/hip_runtime.h>
#include <hip/hip_bf16.h>
#include <hip/hip_fp16.h>

#define T_STEPS 12
#define N_NODES 10000
#define FDIM 128
#define M_ROWS (T_STEPS * N_NODES)

typedef __attribute__((ext_vector_type(8))) short short8v;
typedef __attribute__((ext_vector_type(8))) _Float16 half8v;
typedef __attribute__((ext_vector_type(2))) _Float16 half2v;
typedef __attribute__((ext_vector_type(4))) float f32x4;

// async global->LDS, 16 B per lane; LDS dest is wave-uniform base + lane*16
__device__ __forceinline__ void gload_lds16(const void* g, void* l) {
    __builtin_amdgcn_global_load_lds(
        (const __attribute__((address_space(1))) unsigned int*)g,
        (__attribute__((address_space(3))) unsigned int*)l,
        16, 0, 0);
}

// ---------------- CSR build (counting sort by dst), packed edges ----------------

__global__ __launch_bounds__(256) void k_count(const int* __restrict__ ei, int* __restrict__ cnt, int E) {
    int e = blockIdx.x * 256 + threadIdx.x;
    if (e < E) atomicAdd(&cnt[ei[E + e]], 1);
}

// 1 block, 256 threads; each thread scans a 40-element chunk serially.
__global__ __launch_bounds__(256) void k_scan2(const int* __restrict__ cnt, int* __restrict__ rowptr,
                                               int* __restrict__ cursor) {
    __shared__ int part[256];
    int tid = threadIdx.x;
    const int PER = 40;  // 256*40 = 10240 >= N_NODES
    int base = tid * PER;
    int s = 0;
#pragma unroll 8
    for (int q = 0; q < PER; ++q) {
        int idx = base + q;
        s += (idx < N_NODES) ? cnt[idx] : 0;
    }
    part[tid] = s;
    __syncthreads();
    for (int off = 1; off < 256; off <<= 1) {
        int v = (tid >= off) ? part[tid - off] : 0;
        __syncthreads();
        part[tid] += v;
        __syncthreads();
    }
    int run = (tid > 0) ? part[tid - 1] : 0;
#pragma unroll 8
    for (int q = 0; q < PER; ++q) {
        int idx = base + q;
        if (idx < N_NODES) {
            rowptr[idx] = run;
            cursor[idx] = run;
            run += cnt[idx];
        }
    }
    if (tid == 255) rowptr[N_NODES] = run;
}

__global__ __launch_bounds__(256) void k_fill(const int* __restrict__ ei, const float* __restrict__ ew,
                                              int* __restrict__ cursor, uint2* __restrict__ epack, int E) {
    int e = blockIdx.x * 256 + threadIdx.x;
    if (e < E) {
        int s = ei[e];
        int d = ei[E + e];
        int slot = atomicAdd(&cursor[d], 1);
        epack[slot] = make_uint2((unsigned)s, __builtin_bit_cast(unsigned, ew[e]));
    }
}

__global__ __launch_bounds__(256) void k_dinv(const int* __restrict__ rowptr, const uint2* __restrict__ epack,
                                              float* __restrict__ dinv) {
    int n = blockIdx.x * 256 + threadIdx.x;
    if (n < N_NODES) {
        int r0 = rowptr[n], r1 = rowptr[n + 1];
        float s = 0.f;
        for (int i = r0; i < r1; ++i) s += __builtin_bit_cast(float, epack[i].y);
        dinv[n] = (s > 0.f) ? rsqrtf(s) : 0.f;
    }
}

// finalize: epack[i] = {col*256 (byte offset of fp16 row), bits(dinv[n]*ew*dinv[col])}
__global__ __launch_bounds__(256) void k_scale(const int* __restrict__ rowptr, uint2* __restrict__ epack,
                                               const float* __restrict__ dinv) {
    int n = blockIdx.x * 256 + threadIdx.x;
    if (n < N_NODES) {
        int r0 = rowptr[n], r1 = rowptr[n + 1];
        float dn = dinv[n];
        for (int i = r0; i < r1; ++i) {
            uint2 e = epack[i];
            float v = dn * __builtin_bit_cast(float, e.y) * dinv[e.x];
            epack[i] = make_uint2(e.x * 256u, __builtin_bit_cast(unsigned, v));
        }
    }
}

// ---------------- W pre-split: f32 -> fp16 hi + fp16 lo in MFMA B-frag layout ----------------

__global__ __launch_bounds__(256) void k_wsplit4(const float* __restrict__ Wa, const float* __restrict__ Wb,
                                                 const float* __restrict__ Wc, const float* __restrict__ Wd,
                                                 short* __restrict__ base) {
    int wsel = blockIdx.y;
    const float* W = (wsel == 0) ? Wa : (wsel == 1) ? Wb : (wsel == 2) ? Wc : Wd;
    short* Whf = base + (size_t)wsel * 2 * FDIM * FDIM;
    short* Wlf = Whf + FDIM * FDIM;
    int idx = blockIdx.x * 256 + threadIdx.x;  // 16384
    int k = idx >> 7, col = idx & 127;
    int s = k >> 5, kb = (k >> 3) & 3, j = k & 7;
    float w = W[(size_t)k * FDIM + col];
    _Float16 hi = (_Float16)w;
    _Float16 lo = (_Float16)(w - (float)hi);
    size_t oi = (size_t)(((s * 4 + kb) * 128 + col)) * 8 + j;
    Whf[oi] = __builtin_bit_cast(short, hi);
    Wlf[oi] = __builtin_bit_cast(short, lo);
}

// ---------------- fp16 MFMA GEMM: C[M,128] = A[M,128] @ (Whi+Wlo), LDS-staged W ----------------
// 512 threads = 8 waves; wave owns 32 rows (2 m x 8 n tiles); block = 256 rows.
// W (hi||lo, 64 KB) staged once per block -> 2 blocks/CU = 16 waves/CU = 4/SIMD,
// and W-stage traffic halves vs 256-thread blocks (469 x 64 KB = 30 MB).

template <typename IN_T, typename OUT_T>
__global__ __launch_bounds__(512) void k_gemm_f16(const IN_T* __restrict__ A,
                                                  const short* __restrict__ Whf,
                                                  const short* __restrict__ Wlf,
                                                  OUT_T* __restrict__ C, int Mrows) {
    __shared__ short WsL[2 * FDIM * FDIM];  // hi at 0, lo at 16384 (halfwords)
    int tid = threadIdx.x;
    int wave = tid >> 6, lane = tid & 63;
    int lr = lane & 15, kb = lane >> 4;
    int rbase = blockIdx.x * 256 + wave * 32;

    // stage Whf (32 KB) and Wlf (32 KB) linearly into LDS; 8 waves x 4 chunks each
    {
        const char* srcH = (const char*)Whf;
        const char* srcL = (const char*)Wlf;
        char* dst = (char*)WsL;
#pragma unroll
        for (int it = 0; it < 4; ++it) {
            int chunk = (it * 8 + wave) * 1024;  // 64 lanes x 16 B per wave-issue
            gload_lds16(srcH + chunk + lane * 16, dst + chunk);
            gload_lds16(srcL + chunk + lane * 16, dst + 32768 + chunk);
        }
    }

    f32x4 acc[2][8];
#pragma unroll
    for (int m = 0; m < 2; ++m)
#pragma unroll
        for (int n = 0; n < 8; ++n) acc[m][n] = (f32x4){0.f, 0.f, 0.f, 0.f};

    __syncthreads();  // drains global_load_lds (vmcnt) + barrier

#pragma unroll
    for (int s = 0; s < 4; ++s) {
        half8v a[2];
#pragma unroll
        for (int m = 0; m < 2; ++m) {
            int r = rbase + m * 16 + lr;
            if (r > Mrows - 1) r = Mrows - 1;
            const IN_T* ap = &A[(size_t)r * FDIM + s * 32 + kb * 8];
            if constexpr (sizeof(IN_T) == 4) {
                float4 x0 = *(const float4*)ap;
                float4 x1 = *(const float4*)(ap + 4);
                a[m][0] = (_Float16)x0.x; a[m][1] = (_Float16)x0.y;
                a[m][2] = (_Float16)x0.z; a[m][3] = (_Float16)x0.w;
                a[m][4] = (_Float16)x1.x; a[m][5] = (_Float16)x1.y;
                a[m][6] = (_Float16)x1.z; a[m][7] = (_Float16)x1.w;
            } else {
                a[m] = __builtin_bit_cast(half8v, *(const short8v*)ap);
            }
        }
#pragma unroll
        for (int n = 0; n < 8; ++n) {
            int wo = (((s * 4 + kb) * 128 + n * 16 + lr)) * 8;
            half8v wh = __builtin_bit_cast(half8v, *(const short8v*)&WsL[wo]);
            half8v wl = __builtin_bit_cast(half8v, *(const short8v*)&WsL[16384 + wo]);
#pragma unroll
            for (int m = 0; m < 2; ++m) {
                acc[m][n] = __builtin_amdgcn_mfma_f32_16x16x32_f16(a[m], wh, acc[m][n], 0, 0, 0);
                acc[m][n] = __builtin_amdgcn_mfma_f32_16x16x32_f16(a[m], wl, acc[m][n], 0, 0, 0);
            }
        }
    }
    // D layout: col = lane&15 (+16n), row = rbase + 16m + (lane>>4)*4 + q
#pragma unroll
    for (int m = 0; m < 2; ++m)
#pragma unroll
        for (int q = 0; q < 4; ++q) {
            int r = rbase + m * 16 + kb * 4 + q;
            if (r < Mrows) {
#pragma unroll
                for (int n = 0; n < 8; ++n)
                    C[(size_t)r * FDIM + n * 16 + lr] = (OUT_T)acc[m][n][q];
            }
        }
}

// ---------------- spatial aggregation: XCD-pinned, scalar edge stream, 16-deep gathers ----------------

#define NPB 20
#define NB_HALF 250

__global__ __launch_bounds__(128) void k_aggx(const char* __restrict__ Sbytes,
                                              const int* __restrict__ rowptr,
                                              const uint2* __restrict__ epack,
                                              const float* __restrict__ bias, __half* __restrict__ out,
                                              int do_relu) {
    int bid = blockIdx.x;
    int x = bid & 7;
    int j = bid >> 3;          // 0..749
    int unit = j / NB_HALF;    // 0,1,2
    int nb = j - unit * NB_HALF;
    int t, n0;
    if (unit == 2) { t = 8 + (x >> 1); n0 = (x & 1) * 5000 + nb * NPB; }
    else           { t = x;            n0 = unit * 5000 + nb * NPB; }

    int wave = threadIdx.x >> 6, lane = threadIdx.x & 63;
    const char* St = Sbytes + (size_t)t * N_NODES * 256;  // 256 B per fp16 row
    unsigned lane4 = (unsigned)lane * 4u;
    float b0 = bias[2 * lane], b1 = bias[2 * lane + 1];

    int nbase = n0 + wave * (NPB / 2);
    for (int nn = 0; nn < NPB / 2; ++nn) {
        int n = nbase + nn;
        int r0 = __builtin_amdgcn_readfirstlane(rowptr[n]);
        int r1 = __builtin_amdgcn_readfirstlane(rowptr[n + 1]);
        float a0 = 0.f, a1 = 0.f;
        int i = r0;
        while (i + 16 <= r1) {
            unsigned sx[16]; float sv[16];
#pragma unroll
            for (int q = 0; q < 16; ++q) {
                uint2 e = epack[i + q];
                sx[q] = e.x;
                sv[q] = __builtin_bit_cast(float, e.y);
            }
            unsigned u[16];
#pragma unroll
            for (int q = 0; q < 16; ++q)
                u[q] = *(const unsigned*)(St + (sx[q] + lane4));
#pragma unroll
            for (int q = 0; q < 16; ++q) {
                half2v h = __builtin_bit_cast(half2v, u[q]);
                a0 = fmaf(sv[q], (float)h[0], a0);
                a1 = fmaf(sv[q], (float)h[1], a1);
            }
            i += 16;
        }
        while (i < r1) {
            unsigned sx[8]; float sv[8];
#pragma unroll
            for (int q = 0; q < 8; ++q) {
                int ii = i + q;
                int ic = (ii < r1) ? ii : r1 - 1;
                uint2 e = epack[ic];
                sx[q] = e.x;
                sv[q] = (ii < r1) ? __builtin_bit_cast(float, e.y) : 0.f;
            }
            unsigned u[8];
#pragma unroll
            for (int q = 0; q < 8; ++q)
                u[q] = *(const unsigned*)(St + (sx[q] + lane4));
#pragma unroll
            for (int q = 0; q < 8; ++q) {
                half2v h = __builtin_bit_cast(half2v, u[q]);
                a0 = fmaf(sv[q], (float)h[0], a0);
                a1 = fmaf(sv[q], (float)h[1], a1);
            }
            i += 8;
        }
        float o0 = a0 + b0, o1 = a1 + b1;
        if (do_relu) { o0 = fmaxf(o0, 0.f); o1 = fmaxf(o1, 0.f); }
        __half2 h = __floats2half2_rn(o0, o1);
        unsigned uo = __builtin_bit_cast(unsigned, h);
        __builtin_nontemporal_store(uo, (unsigned*)&out[((size_t)t * N_NODES + n) * FDIM + 2 * lane]);
    }
}

// ---------------- temporal aggregation (chain graph, closed-form norm), fp16 I/O ----------------

__device__ __forceinline__ void tagg_core(float2 (&s)[T_STEPS], float b0, float b1,
                                          float2 (&o)[T_STEPS]) {
    const float IS2 = 0.70710678118654752f;
#pragma unroll
    for (int t = 0; t < T_STEPS; ++t) {
        float dt = (t == 0 || t == T_STEPS - 1) ? 1.f : IS2;
        float a0 = 0.f, a1 = 0.f;
        if (t > 0) {
            float dp = (t - 1 == 0) ? 1.f : IS2;
            a0 += dp * s[t - 1].x; a1 += dp * s[t - 1].y;
        }
        if (t < T_STEPS - 1) {
            float dn = (t + 1 == T_STEPS - 1) ? 1.f : IS2;
            a0 += dn * s[t + 1].x; a1 += dn * s[t + 1].y;
        }
        o[t].x = dt * a0 + b0;
        o[t].y = dt * a1 + b1;
    }
}

__global__ __launch_bounds__(256) void k_tagg_relu(const __half2* __restrict__ S2,
                                                   const float* __restrict__ bias,
                                                   __half2* __restrict__ out) {
    int p = blockIdx.x * 256 + threadIdx.x;
    if (p >= N_NODES * 64) return;
    int c2 = p & 63;
    float b0 = bias[2 * c2], b1 = bias[2 * c2 + 1];
    float2 s[T_STEPS], o[T_STEPS];
#pragma unroll
    for (int t = 0; t < T_STEPS; ++t) s[t] = __half22float2(S2[(size_t)t * N_NODES * 64 + p]);
    tagg_core(s, b0, b1, o);
#pragma unroll
    for (int t = 0; t < T_STEPS; ++t) {
        float o0 = fmaxf(o[t].x, 0.f), o1 = fmaxf(o[t].y, 0.f);
        out[(size_t)t * N_NODES * 64 + p] = __floats2half2_rn(o0, o1);
    }
}

__global__ __launch_bounds__(256) void k_tagg_tanh(const __half2* __restrict__ S2,
                                                   const float* __restrict__ bias,
                                                   float* __restrict__ out) {
    int p = blockIdx.x * 256 + threadIdx.x;
    if (p >= N_NODES * 64) return;
    int c2 = p & 63;
    float b0 = bias[2 * c2], b1 = bias[2 * c2 + 1];
    float2 s[T_STEPS], o[T_STEPS];
#pragma unroll
    for (int t = 0; t < T_STEPS; ++t) s[t] = __half22float2(S2[(size_t)t * N_NODES * 64 + p]);
    tagg_core(s, b0, b1, o);
#pragma unroll
    for (int t = 0; t < T_STEPS; ++t) {
        float2 r = make_float2(tanhf(o[t].x), tanhf(o[t].y));
        *(float2*)&out[(size_t)t * N_NODES * FDIM + 2 * (size_t)p] = r;
    }
}

// ---------------- launch ----------------

extern "C" void kernel_launch(void* const* d_in, const int* in_sizes, int n_in,
                              void* d_out, int out_size, void* d_ws, size_t ws_size,
                              hipStream_t stream) {
    const float* x   = (const float*)d_in[0];
    const int*   ei  = (const int*)d_in[1];
    const float* ew  = (const float*)d_in[2];
    const float* W1  = (const float*)d_in[3];
    const float* b1  = (const float*)d_in[4];
    const float* W2  = (const float*)d_in[5];
    const float* b2  = (const float*)d_in[6];
    const float* Wt1 = (const float*)d_in[7];
    const float* bt1 = (const float*)d_in[8];
    const float* Wt2 = (const float*)d_in[9];
    const float* bt2 = (const float*)d_in[10];
    float*  outF = (float*)d_out;
    __half* Sh   = (__half*)d_out;  // fp16 GEMM outputs alias front half of d_out
    const int E = in_sizes[2];

    char* w = (char*)d_ws;
    __half* bufH = (__half*)w;                 // fp16 agg/tagg outputs (GEMM A inputs)
    size_t off   = (size_t)M_ROWS * FDIM * 2;
    __half* S2h  = (__half*)(w + off); off += (size_t)M_ROWS * FDIM * 2;  // GEMM4 out
    int* cnt     = (int*)(w + off); off += (size_t)N_NODES * 4;
    int* rowptr  = (int*)(w + off); off += (size_t)(N_NODES + 1) * 4;
    int* cursor  = (int*)(w + off); off += (size_t)N_NODES * 4;
    uint2* epack = (uint2*)(w + off); off += (size_t)E * 8;
    float* dinv  = (float*)(w + off); off += (size_t)N_NODES * 4;
    short* Wsp   = (short*)(w + off); off += (size_t)8 * FDIM * FDIM * 2;  // 4 x (hi,lo)
    const size_t WSZ = (size_t)FDIM * FDIM;
    short* W1h = Wsp;            short* W1l = Wsp + WSZ;
    short* W2h = Wsp + 2 * WSZ;  short* W2l = Wsp + 3 * WSZ;
    short* Wt1h = Wsp + 4 * WSZ; short* Wt1l = Wsp + 5 * WSZ;
    short* Wt2h = Wsp + 6 * WSZ; short* Wt2l = Wsp + 7 * WSZ;

    hipMemsetAsync(cnt, 0, (size_t)N_NODES * 4, stream);
    int eb = (E + 255) / 256;
    int nb = (N_NODES + 255) / 256;
    k_count<<<eb, 256, 0, stream>>>(ei, cnt, E);
    k_scan2<<<1, 256, 0, stream>>>(cnt, rowptr, cursor);
    k_fill<<<eb, 256, 0, stream>>>(ei, ew, cursor, epack, E);
    k_dinv<<<nb, 256, 0, stream>>>(rowptr, epack, dinv);
    k_scale<<<nb, 256, 0, stream>>>(rowptr, epack, dinv);

    dim3 wgrid((FDIM * FDIM) / 256, 4);
    k_wsplit4<<<wgrid, 256, 0, stream>>>(W1, W2, Wt1, Wt2, Wsp);

    int gb = (M_ROWS + 255) / 256;    // 469 blocks, 256 rows each (8 waves x 32 rows)
    int tb = (N_NODES * 64 + 255) / 256;
    int ab = 8 * 3 * NB_HALF;         // 6000 blocks, XCD-pinned decode inside

    // spatial layer 1: Sh = fp16(X@W1) ; bufH = fp16(relu(A*Sh + b1))
    k_gemm_f16<float, __half><<<gb, 512, 0, stream>>>(x, W1h, W1l, Sh, M_ROWS);
    k_aggx<<<ab, 128, 0, stream>>>((const char*)Sh, rowptr, epack, b1, bufH, 1);
    // spatial layer 2
    k_gemm_f16<__half, __half><<<gb, 512, 0, stream>>>(bufH, W2h, W2l, Sh, M_ROWS);
    k_aggx<<<ab, 128, 0, stream>>>((const char*)Sh, rowptr, epack, b2, bufH, 0);
    // temporal layer 1: Sh = fp16(bufH@Wt1) ; bufH = fp16(relu(Tagg(Sh)+bt1))
    k_gemm_f16<__half, __half><<<gb, 512, 0, stream>>>(bufH, Wt1h, Wt1l, Sh, M_ROWS);
    k_tagg_relu<<<tb, 256, 0, stream>>>((const __half2*)Sh, bt1, (__half2*)bufH);
    // temporal layer 2: S2h = fp16(bufH@Wt2) ; out = tanh(Tagg(S2h)+bt2)  (f32 to d_out)
    k_gemm_f16<__half, __half><<<gb, 512, 0, stream>>>(bufH, Wt2h, Wt2l, S2h, M_ROWS);
    k_tagg_tanh<<<tb, 256, 0, stream>>>((const __half2*)S2h, bt2, outF);
}

// Round 15
// 248.828 us; speedup vs baseline: 1.2301x; 1.0481x over previous
//
#include <hip/hip_runtime.h>
#include <hip/hip_bf16.h>
#include <hip/hip_fp16.h>

#define T_STEPS 12
#define N_NODES 10000
#define FDIM 128
#define M_ROWS (T_STEPS * N_NODES)

typedef __attribute__((ext_vector_type(8))) short short8v;
typedef __attribute__((ext_vector_type(8))) _Float16 half8v;
typedef __attribute__((ext_vector_type(2))) _Float16 half2v;
typedef __attribute__((ext_vector_type(4))) float f32x4;

// async global->LDS, 16 B per lane; LDS dest is wave-uniform base + lane*16
__device__ __forceinline__ void gload_lds16(const void* g, void* l) {
    __builtin_amdgcn_global_load_lds(
        (const __attribute__((address_space(1))) unsigned int*)g,
        (__attribute__((address_space(3))) unsigned int*)l,
        16, 0, 0);
}

// ---------------- CSR build (counting sort by dst), packed edges ----------------

__global__ __launch_bounds__(256) void k_count(const int* __restrict__ ei, int* __restrict__ cnt, int E) {
    int e = blockIdx.x * 256 + threadIdx.x;
    if (e < E) atomicAdd(&cnt[ei[E + e]], 1);
}

// 1 block, 256 threads; each thread scans a 40-element chunk serially.
__global__ __launch_bounds__(256) void k_scan2(const int* __restrict__ cnt, int* __restrict__ rowptr,
                                               int* __restrict__ cursor) {
    __shared__ int part[256];
    int tid = threadIdx.x;
    const int PER = 40;  // 256*40 = 10240 >= N_NODES
    int base = tid * PER;
    int s = 0;
#pragma unroll 8
    for (int q = 0; q < PER; ++q) {
        int idx = base + q;
        s += (idx < N_NODES) ? cnt[idx] : 0;
    }
    part[tid] = s;
    __syncthreads();
    for (int off = 1; off < 256; off <<= 1) {
        int v = (tid >= off) ? part[tid - off] : 0;
        __syncthreads();
        part[tid] += v;
        __syncthreads();
    }
    int run = (tid > 0) ? part[tid - 1] : 0;
#pragma unroll 8
    for (int q = 0; q < PER; ++q) {
        int idx = base + q;
        if (idx < N_NODES) {
            rowptr[idx] = run;
            cursor[idx] = run;
            run += cnt[idx];
        }
    }
    if (tid == 255) rowptr[N_NODES] = run;
}

__global__ __launch_bounds__(256) void k_fill(const int* __restrict__ ei, const float* __restrict__ ew,
                                              int* __restrict__ cursor, uint2* __restrict__ epack, int E) {
    int e = blockIdx.x * 256 + threadIdx.x;
    if (e < E) {
        int s = ei[e];
        int d = ei[E + e];
        int slot = atomicAdd(&cursor[d], 1);
        epack[slot] = make_uint2((unsigned)s, __builtin_bit_cast(unsigned, ew[e]));
    }
}

__global__ __launch_bounds__(256) void k_dinv(const int* __restrict__ rowptr, const uint2* __restrict__ epack,
                                              float* __restrict__ dinv) {
    int n = blockIdx.x * 256 + threadIdx.x;
    if (n < N_NODES) {
        int r0 = rowptr[n], r1 = rowptr[n + 1];
        float s = 0.f;
        for (int i = r0; i < r1; ++i) s += __builtin_bit_cast(float, epack[i].y);
        dinv[n] = (s > 0.f) ? rsqrtf(s) : 0.f;
    }
}

// finalize: epack[i] = {col*256 (byte offset of fp16 row), bits(dinv[n]*ew*dinv[col])}
__global__ __launch_bounds__(256) void k_scale(const int* __restrict__ rowptr, uint2* __restrict__ epack,
                                               const float* __restrict__ dinv) {
    int n = blockIdx.x * 256 + threadIdx.x;
    if (n < N_NODES) {
        int r0 = rowptr[n], r1 = rowptr[n + 1];
        float dn = dinv[n];
        for (int i = r0; i < r1; ++i) {
            uint2 e = epack[i];
            float v = dn * __builtin_bit_cast(float, e.y) * dinv[e.x];
            epack[i] = make_uint2(e.x * 256u, __builtin_bit_cast(unsigned, v));
        }
    }
}

// ---------------- W pre-convert: f32 -> fp16 (RNE) in MFMA B-frag layout ----------------
// frag index: out[((s*4+kb)*128 + col)*8 + j] = W[(s*32 + kb*8 + j)][col]
// A enters MFMA as exact fp16; W-fp16 rounding adds ~4e-4 RMS per layer (threshold 8.8e-3).

__global__ __launch_bounds__(256) void k_wsplit4(const float* __restrict__ Wa, const float* __restrict__ Wb,
                                                 const float* __restrict__ Wc, const float* __restrict__ Wd,
                                                 short* __restrict__ base) {
    int wsel = blockIdx.y;
    const float* W = (wsel == 0) ? Wa : (wsel == 1) ? Wb : (wsel == 2) ? Wc : Wd;
    short* Whf = base + (size_t)wsel * FDIM * FDIM;
    int idx = blockIdx.x * 256 + threadIdx.x;  // 16384
    int k = idx >> 7, col = idx & 127;
    int s = k >> 5, kb = (k >> 3) & 3, j = k & 7;
    _Float16 hi = (_Float16)W[(size_t)k * FDIM + col];
    size_t oi = (size_t)(((s * 4 + kb) * 128 + col)) * 8 + j;
    Whf[oi] = __builtin_bit_cast(short, hi);
}

// ---------------- fp16 MFMA GEMM: C[M,128] = A[M,128] @ W16, LDS-staged W ----------------
// 512 threads = 8 waves; wave owns 32 rows (2 m x 8 n tiles); block = 256 rows.
// W (fp16, 32 KB) staged once per block -> 4 blocks/CU = 32 waves/CU = 8/SIMD.
// Inner loop per wave: 32 ds_read_b128 + 64 MFMA (1-term, Wlo dropped).

template <typename IN_T, typename OUT_T>
__global__ __launch_bounds__(512) void k_gemm_f16(const IN_T* __restrict__ A,
                                                  const short* __restrict__ Whf,
                                                  OUT_T* __restrict__ C, int Mrows) {
    __shared__ short WsL[FDIM * FDIM];  // 32 KB
    int tid = threadIdx.x;
    int wave = tid >> 6, lane = tid & 63;
    int lr = lane & 15, kb = lane >> 4;
    int rbase = blockIdx.x * 256 + wave * 32;

    // stage Whf (32 KB) linearly into LDS; 8 waves x 4 chunks of 1 KB
    {
        const char* src = (const char*)Whf;
        char* dst = (char*)WsL;
#pragma unroll
        for (int it = 0; it < 4; ++it) {
            int chunk = (it * 8 + wave) * 1024;  // 64 lanes x 16 B per wave-issue
            gload_lds16(src + chunk + lane * 16, dst + chunk);
        }
    }

    f32x4 acc[2][8];
#pragma unroll
    for (int m = 0; m < 2; ++m)
#pragma unroll
        for (int n = 0; n < 8; ++n) acc[m][n] = (f32x4){0.f, 0.f, 0.f, 0.f};

    __syncthreads();  // drains global_load_lds (vmcnt) + barrier

#pragma unroll
    for (int s = 0; s < 4; ++s) {
        half8v a[2];
#pragma unroll
        for (int m = 0; m < 2; ++m) {
            int r = rbase + m * 16 + lr;
            if (r > Mrows - 1) r = Mrows - 1;
            const IN_T* ap = &A[(size_t)r * FDIM + s * 32 + kb * 8];
            if constexpr (sizeof(IN_T) == 4) {
                float4 x0 = *(const float4*)ap;
                float4 x1 = *(const float4*)(ap + 4);
                a[m][0] = (_Float16)x0.x; a[m][1] = (_Float16)x0.y;
                a[m][2] = (_Float16)x0.z; a[m][3] = (_Float16)x0.w;
                a[m][4] = (_Float16)x1.x; a[m][5] = (_Float16)x1.y;
                a[m][6] = (_Float16)x1.z; a[m][7] = (_Float16)x1.w;
            } else {
                a[m] = __builtin_bit_cast(half8v, *(const short8v*)ap);
            }
        }
#pragma unroll
        for (int n = 0; n < 8; ++n) {
            int wo = (((s * 4 + kb) * 128 + n * 16 + lr)) * 8;
            half8v wh = __builtin_bit_cast(half8v, *(const short8v*)&WsL[wo]);
#pragma unroll
            for (int m = 0; m < 2; ++m)
                acc[m][n] = __builtin_amdgcn_mfma_f32_16x16x32_f16(a[m], wh, acc[m][n], 0, 0, 0);
        }
    }
    // D layout: col = lane&15 (+16n), row = rbase + 16m + (lane>>4)*4 + q
#pragma unroll
    for (int m = 0; m < 2; ++m)
#pragma unroll
        for (int q = 0; q < 4; ++q) {
            int r = rbase + m * 16 + kb * 4 + q;
            if (r < Mrows) {
#pragma unroll
                for (int n = 0; n < 8; ++n)
                    C[(size_t)r * FDIM + n * 16 + lr] = (OUT_T)acc[m][n][q];
            }
        }
}

// ---------------- spatial aggregation: XCD-pinned, scalar edge stream, 16-deep gathers ----------------

#define NPB 20
#define NB_HALF 250

__global__ __launch_bounds__(128) void k_aggx(const char* __restrict__ Sbytes,
                                              const int* __restrict__ rowptr,
                                              const uint2* __restrict__ epack,
                                              const float* __restrict__ bias, __half* __restrict__ out,
                                              int do_relu) {
    int bid = blockIdx.x;
    int x = bid & 7;
    int j = bid >> 3;          // 0..749
    int unit = j / NB_HALF;    // 0,1,2
    int nb = j - unit * NB_HALF;
    int t, n0;
    if (unit == 2) { t = 8 + (x >> 1); n0 = (x & 1) * 5000 + nb * NPB; }
    else           { t = x;            n0 = unit * 5000 + nb * NPB; }

    int wave = threadIdx.x >> 6, lane = threadIdx.x & 63;
    const char* St = Sbytes + (size_t)t * N_NODES * 256;  // 256 B per fp16 row
    unsigned lane4 = (unsigned)lane * 4u;
    float b0 = bias[2 * lane], b1 = bias[2 * lane + 1];

    int nbase = n0 + wave * (NPB / 2);
    for (int nn = 0; nn < NPB / 2; ++nn) {
        int n = nbase + nn;
        int r0 = __builtin_amdgcn_readfirstlane(rowptr[n]);
        int r1 = __builtin_amdgcn_readfirstlane(rowptr[n + 1]);
        float a0 = 0.f, a1 = 0.f;
        int i = r0;
        while (i + 16 <= r1) {
            unsigned sx[16]; float sv[16];
#pragma unroll
            for (int q = 0; q < 16; ++q) {
                uint2 e = epack[i + q];
                sx[q] = e.x;
                sv[q] = __builtin_bit_cast(float, e.y);
            }
            unsigned u[16];
#pragma unroll
            for (int q = 0; q < 16; ++q)
                u[q] = *(const unsigned*)(St + (sx[q] + lane4));
#pragma unroll
            for (int q = 0; q < 16; ++q) {
                half2v h = __builtin_bit_cast(half2v, u[q]);
                a0 = fmaf(sv[q], (float)h[0], a0);
                a1 = fmaf(sv[q], (float)h[1], a1);
            }
            i += 16;
        }
        while (i < r1) {
            unsigned sx[8]; float sv[8];
#pragma unroll
            for (int q = 0; q < 8; ++q) {
                int ii = i + q;
                int ic = (ii < r1) ? ii : r1 - 1;
                uint2 e = epack[ic];
                sx[q] = e.x;
                sv[q] = (ii < r1) ? __builtin_bit_cast(float, e.y) : 0.f;
            }
            unsigned u[8];
#pragma unroll
            for (int q = 0; q < 8; ++q)
                u[q] = *(const unsigned*)(St + (sx[q] + lane4));
#pragma unroll
            for (int q = 0; q < 8; ++q) {
                half2v h = __builtin_bit_cast(half2v, u[q]);
                a0 = fmaf(sv[q], (float)h[0], a0);
                a1 = fmaf(sv[q], (float)h[1], a1);
            }
            i += 8;
        }
        float o0 = a0 + b0, o1 = a1 + b1;
        if (do_relu) { o0 = fmaxf(o0, 0.f); o1 = fmaxf(o1, 0.f); }
        __half2 h = __floats2half2_rn(o0, o1);
        unsigned uo = __builtin_bit_cast(unsigned, h);
        __builtin_nontemporal_store(uo, (unsigned*)&out[((size_t)t * N_NODES + n) * FDIM + 2 * lane]);
    }
}

// ---------------- temporal aggregation (chain graph, closed-form norm), fp16 I/O ----------------

__device__ __forceinline__ void tagg_core(float2 (&s)[T_STEPS], float b0, float b1,
                                          float2 (&o)[T_STEPS]) {
    const float IS2 = 0.70710678118654752f;
#pragma unroll
    for (int t = 0; t < T_STEPS; ++t) {
        float dt = (t == 0 || t == T_STEPS - 1) ? 1.f : IS2;
        float a0 = 0.f, a1 = 0.f;
        if (t > 0) {
            float dp = (t - 1 == 0) ? 1.f : IS2;
            a0 += dp * s[t - 1].x; a1 += dp * s[t - 1].y;
        }
        if (t < T_STEPS - 1) {
            float dn = (t + 1 == T_STEPS - 1) ? 1.f : IS2;
            a0 += dn * s[t + 1].x; a1 += dn * s[t + 1].y;
        }
        o[t].x = dt * a0 + b0;
        o[t].y = dt * a1 + b1;
    }
}

__global__ __launch_bounds__(256) void k_tagg_relu(const __half2* __restrict__ S2,
                                                   const float* __restrict__ bias,
                                                   __half2* __restrict__ out) {
    int p = blockIdx.x * 256 + threadIdx.x;
    if (p >= N_NODES * 64) return;
    int c2 = p & 63;
    float b0 = bias[2 * c2], b1 = bias[2 * c2 + 1];
    float2 s[T_STEPS], o[T_STEPS];
#pragma unroll
    for (int t = 0; t < T_STEPS; ++t) s[t] = __half22float2(S2[(size_t)t * N_NODES * 64 + p]);
    tagg_core(s, b0, b1, o);
#pragma unroll
    for (int t = 0; t < T_STEPS; ++t) {
        float o0 = fmaxf(o[t].x, 0.f), o1 = fmaxf(o[t].y, 0.f);
        out[(size_t)t * N_NODES * 64 + p] = __floats2half2_rn(o0, o1);
    }
}

__global__ __launch_bounds__(256) void k_tagg_tanh(const __half2* __restrict__ S2,
                                                   const float* __restrict__ bias,
                                                   float* __restrict__ out) {
    int p = blockIdx.x * 256 + threadIdx.x;
    if (p >= N_NODES * 64) return;
    int c2 = p & 63;
    float b0 = bias[2 * c2], b1 = bias[2 * c2 + 1];
    float2 s[T_STEPS], o[T_STEPS];
#pragma unroll
    for (int t = 0; t < T_STEPS; ++t) s[t] = __half22float2(S2[(size_t)t * N_NODES * 64 + p]);
    tagg_core(s, b0, b1, o);
#pragma unroll
    for (int t = 0; t < T_STEPS; ++t) {
        float2 r = make_float2(tanhf(o[t].x), tanhf(o[t].y));
        *(float2*)&out[(size_t)t * N_NODES * FDIM + 2 * (size_t)p] = r;
    }
}

// ---------------- launch ----------------

extern "C" void kernel_launch(void* const* d_in, const int* in_sizes, int n_in,
                              void* d_out, int out_size, void* d_ws, size_t ws_size,
                              hipStream_t stream) {
    const float* x   = (const float*)d_in[0];
    const int*   ei  = (const int*)d_in[1];
    const float* ew  = (const float*)d_in[2];
    const float* W1  = (const float*)d_in[3];
    const float* b1  = (const float*)d_in[4];
    const float* W2  = (const float*)d_in[5];
    const float* b2  = (const float*)d_in[6];
    const float* Wt1 = (const float*)d_in[7];
    const float* bt1 = (const float*)d_in[8];
    const float* Wt2 = (const float*)d_in[9];
    const float* bt2 = (const float*)d_in[10];
    float*  outF = (float*)d_out;
    __half* Sh   = (__half*)d_out;  // fp16 GEMM outputs alias front half of d_out
    const int E = in_sizes[2];

    char* w = (char*)d_ws;
    __half* bufH = (__half*)w;                 // fp16 agg/tagg outputs (GEMM A inputs)
    size_t off   = (size_t)M_ROWS * FDIM * 2;
    __half* S2h  = (__half*)(w + off); off += (size_t)M_ROWS * FDIM * 2;  // GEMM4 out
    int* cnt     = (int*)(w + off); off += (size_t)N_NODES * 4;
    int* rowptr  = (int*)(w + off); off += (size_t)(N_NODES + 1) * 4;
    int* cursor  = (int*)(w + off); off += (size_t)N_NODES * 4;
    uint2* epack = (uint2*)(w + off); off += (size_t)E * 8;
    float* dinv  = (float*)(w + off); off += (size_t)N_NODES * 4;
    short* Wsp   = (short*)(w + off); off += (size_t)4 * FDIM * FDIM * 2;  // 4 x fp16 frag
    const size_t WSZ = (size_t)FDIM * FDIM;
    short* W1h  = Wsp;
    short* W2h  = Wsp + WSZ;
    short* Wt1h = Wsp + 2 * WSZ;
    short* Wt2h = Wsp + 3 * WSZ;

    hipMemsetAsync(cnt, 0, (size_t)N_NODES * 4, stream);
    int eb = (E + 255) / 256;
    int nb = (N_NODES + 255) / 256;
    k_count<<<eb, 256, 0, stream>>>(ei, cnt, E);
    k_scan2<<<1, 256, 0, stream>>>(cnt, rowptr, cursor);
    k_fill<<<eb, 256, 0, stream>>>(ei, ew, cursor, epack, E);
    k_dinv<<<nb, 256, 0, stream>>>(rowptr, epack, dinv);
    k_scale<<<nb, 256, 0, stream>>>(rowptr, epack, dinv);

    dim3 wgrid((FDIM * FDIM) / 256, 4);
    k_wsplit4<<<wgrid, 256, 0, stream>>>(W1, W2, Wt1, Wt2, Wsp);

    int gb = (M_ROWS + 255) / 256;    // 469 blocks, 256 rows each (8 waves x 32 rows)
    int tb = (N_NODES * 64 + 255) / 256;
    int ab = 8 * 3 * NB_HALF;         // 6000 blocks, XCD-pinned decode inside

    // spatial layer 1: Sh = fp16(X@W1) ; bufH = fp16(relu(A*Sh + b1))
    k_gemm_f16<float, __half><<<gb, 512, 0, stream>>>(x, W1h, Sh, M_ROWS);
    k_aggx<<<ab, 128, 0, stream>>>((const char*)Sh, rowptr, epack, b1, bufH, 1);
    // spatial layer 2
    k_gemm_f16<__half, __half><<<gb, 512, 0, stream>>>(bufH, W2h, Sh, M_ROWS);
    k_aggx<<<ab, 128, 0, stream>>>((const char*)Sh, rowptr, epack, b2, bufH, 0);
    // temporal layer 1: Sh = fp16(bufH@Wt1) ; bufH = fp16(relu(Tagg(Sh)+bt1))
    k_gemm_f16<__half, __half><<<gb, 512, 0, stream>>>(bufH, Wt1h, Sh, M_ROWS);
    k_tagg_relu<<<tb, 256, 0, stream>>>((const __half2*)Sh, bt1, (__half2*)bufH);
    // temporal layer 2: S2h = fp16(bufH@Wt2) ; out = tanh(Tagg(S2h)+bt2)  (f32 to d_out)
    k_gemm_f16<__half, __half><<<gb, 512, 0, stream>>>(bufH, Wt2h, S2h, M_ROWS);
    k_tagg_tanh<<<tb, 256, 0, stream>>>((const __half2*)S2h, bt2, outF);
}